// Round 9
// baseline (404.863 us; speedup 1.0000x reference)
//
#include <hip/hip_runtime.h>
#include <hip/hip_bf16.h>
#include <math.h>

typedef unsigned short u16;
typedef __attribute__((ext_vector_type(8))) short short8;   // 8 bf16 (4 VGPRs)
typedef __attribute__((ext_vector_type(4))) float f32x4;

#define N_TOK   8192
#define N_HEADS 4
#define KDIM    512
#define HALFD   256
#define VDIM    512
#define SUBK    512
#define NCAND   16

__device__ __forceinline__ u16 f2bf(float f) {
    unsigned u = __float_as_uint(f);
    u += 0x7fffu + ((u >> 16) & 1u);
    return (u16)(u >> 16);
}

__device__ __forceinline__ unsigned med3u(unsigned a, unsigned b, unsigned c) {
    unsigned d;
    asm("v_med3_u32 %0, %1, %2, %3" : "=v"(d) : "v"(a), "v"(b), "v"(c));
    return d;
}

// ---------------- Kernel A: f32 -> bf16 bits (keys only, tiny) ----------------
__global__ void k_convert(const float* __restrict__ in, u16* __restrict__ out, int n4) {
    int i = blockIdx.x * blockDim.x + threadIdx.x;
    int stride = gridDim.x * blockDim.x;
    for (; i < n4; i += stride) {
        float4 v = ((const float4*)in)[i];
        unsigned a = (unsigned)f2bf(v.x) | ((unsigned)f2bf(v.y) << 16);
        unsigned b = (unsigned)f2bf(v.z) | ((unsigned)f2bf(v.w) << 16);
        ((uint2*)out)[i] = make_uint2(a, b);
    }
}

// ================= score body: bf16 MFMA + packed-key exact top-16 =================
// 256 threads. Tokens [n0, n0+16), group (h, half). sc = 8208-u32 LDS arena.
__device__ __forceinline__ void score_body(
    const float* __restrict__ query, const u16* __restrict__ kb,
    int* __restrict__ cand, int n0, int h, int half, int tid, unsigned* sc)
{
    const int wave = tid >> 6, l = tid & 63;
    const int lr = l & 15, lk = l >> 4;

    const float* qbase = query + (size_t)(n0 + lr) * (N_HEADS * KDIM)
                       + h * KDIM + half * HALFD + lk * 8;
    short8 a[8];
#pragma unroll
    for (int kf = 0; kf < 8; ++kf) {
        float4 q0 = *(const float4*)(qbase + kf * 32);
        float4 q1 = *(const float4*)(qbase + kf * 32 + 4);
        short8 t;
        t[0] = (short)f2bf(q0.x); t[1] = (short)f2bf(q0.y);
        t[2] = (short)f2bf(q0.z); t[3] = (short)f2bf(q0.w);
        t[4] = (short)f2bf(q1.x); t[5] = (short)f2bf(q1.y);
        t[6] = (short)f2bf(q1.z); t[7] = (short)f2bf(q1.w);
        a[kf] = t;
    }

    const u16* kbase = kb + (size_t)(half * N_HEADS + h) * SUBK * HALFD;
#pragma unroll
    for (int t = 0; t < 8; ++t) {
        const int st = wave * 8 + t;
        const u16* kp = kbase + (size_t)(st * 16 + lr) * HALFD + lk * 8;
        short8 b[8];
#pragma unroll
        for (int kf = 0; kf < 8; ++kf)
            b[kf] = *(const short8*)(kp + kf * 32);
        f32x4 acc = {0.f, 0.f, 0.f, 0.f};
#pragma unroll
        for (int kf = 0; kf < 8; ++kf)
            acc = __builtin_amdgcn_mfma_f32_16x16x32_bf16(a[kf], b[kf], acc, 0, 0, 0);
        // D layout: col = lane&15 (key), row = (lane>>4)*4 + reg (q row)
#pragma unroll
        for (int r = 0; r < 4; ++r) {
            unsigned ub = __float_as_uint(acc[r]);
            unsigned key = ub ^ ((unsigned)((int)ub >> 31) | 0x80000000u);
            key = (key & 0xFFFFFE00u) | (unsigned)(st * 16 + lr);
            sc[(lk * 4 + r) * 513 + st * 16 + lr] = key;
        }
    }
    __syncthreads();

    const int row = tid >> 4, sub = tid & 15;
    unsigned tv[NCAND];
#pragma unroll
    for (int j = 0; j < NCAND; ++j) tv[j] = 0u;
    const int base = row * 513 + sub;
#pragma unroll
    for (int t = 0; t < 32; ++t) {
        unsigned v = sc[base + (t << 4)];
#pragma unroll
        for (int j = NCAND - 1; j >= 1; --j)
            tv[j] = med3u(tv[j - 1], tv[j], v);
        tv[0] = (tv[0] > v) ? tv[0] : v;
    }

    unsigned keep = 0;
#pragma unroll
    for (int r = 0; r < NCAND; ++r) {
        unsigned w = tv[0];
#pragma unroll
        for (int d = 1; d < 16; d <<= 1) {
            unsigned o = __shfl_xor(w, d, 16);
            w = (o > w) ? o : w;
        }
        if (sub == r) keep = w;
        bool pop = (tv[0] == w);
#pragma unroll
        for (int j = 0; j < NCAND - 1; ++j) tv[j] = pop ? tv[j + 1] : tv[j];
        tv[NCAND - 1] = pop ? 0u : tv[NCAND - 1];
    }
    const int n = n0 + row;
    cand[((size_t)n * 8 + (h * 2 + half)) * NCAND + sub] = (int)(keep & 0x1FFu);
}

// ====== select+gather body: f64 refine + 2-stage top-8 + softmax + gather ======
// 256 threads, one token n. sm = >=11008 B LDS arena.
__device__ __forceinline__ void sg_body(
    const float* __restrict__ query, const float* __restrict__ keys,
    const float* __restrict__ values, const int* __restrict__ cand,
    float* __restrict__ out, int n, int tid, unsigned char* sm)
{
    double* rv     = (double*)(sm);           // 8*16*8   = 1024
    int*    ri     = (int*)(sm + 1024);       // 8*16*4   = 512
    double* tsv    = (double*)(sm + 1536);    // 8*8*8    = 512
    int*    tsi    = (int*)(sm + 2048);       // 8*8*4    = 256
    double* s_comb = (double*)(sm + 2304);    // 32*8     = 256
    int*    sgi    = (int*)(sm + 2560);       // 128
    float*  wsm    = (float*)(sm + 2688);     // 128
    float*  part   = (float*)(sm + 2816);     // 4*512*4  = 8192  -> 11008 total

    // Phase 1: f64 refinement, 2 threads per candidate dot (128 dims each)
    {
        const int dot = tid >> 1, pt = tid & 1;
        const int g = dot >> 4, j = dot & 15;
        const int h = g >> 1, half = g & 1;
        const int sidx = cand[((size_t)n * 8 + g) * NCAND + j];
        const float* qrow = query + (size_t)n * (N_HEADS * KDIM) + h * KDIM + half * HALFD + pt * 128;
        const float* krow = keys + ((size_t)(half * N_HEADS + h) * SUBK + sidx) * HALFD + pt * 128;
        double a0 = 0, a1 = 0, a2 = 0, a3 = 0;
#pragma unroll 8
        for (int d = 0; d < 128; d += 4) {
            float4 qv = *(const float4*)(qrow + d);
            float4 kv = *(const float4*)(krow + d);
            a0 = fma((double)qv.x, (double)kv.x, a0);
            a1 = fma((double)qv.y, (double)kv.y, a1);
            a2 = fma((double)qv.z, (double)kv.z, a2);
            a3 = fma((double)qv.w, (double)kv.w, a3);
        }
        double s = (a0 + a1) + (a2 + a3);
        double o = __shfl_xor(s, 1);
        if (pt == 0) { rv[g * 16 + j] = s + o; ri[g * 16 + j] = sidx; }
    }
    __syncthreads();

    // Phase 2: top-8 of 16 per group (tie -> lowest j)
    if (tid < 128) {
        const int g = tid >> 4, j = tid & 15;
        double v = rv[g * 16 + j];
        const int idx = ri[g * 16 + j];
        for (int r = 0; r < 8; ++r) {
            double bv = v; int bj = j;
#pragma unroll
            for (int d = 1; d < 16; d <<= 1) {
                double ov = __shfl_xor(bv, d, 16);
                int    oj = __shfl_xor(bj, d, 16);
                if (ov > bv || (ov == bv && oj < bj)) { bv = ov; bj = oj; }
            }
            int widx = __shfl(idx, bj, 16);
            if (j == r) { tsv[g * 8 + r] = bv; tsi[g * 8 + r] = widx; }
            if (j == bj) v = -1e300;
        }
    }
    __syncthreads();

    // Phase 3: per head (one wave each), top-8 of 64 combos (tie -> lowest flat f)
    {
        const int h = tid >> 6, f = tid & 63;
        double c = tsv[h * 16 + (f >> 3)] + tsv[(h * 2 + 1) * 8 + (f & 7)];
        for (int r = 0; r < 8; ++r) {
            double bv = c; int bf = f;
#pragma unroll
            for (int d = 1; d < 64; d <<= 1) {
                double ov = __shfl_xor(bv, d, 64);
                int    of = __shfl_xor(bf, d, 64);
                if (ov > bv || (ov == bv && of < bf)) { bv = ov; bf = of; }
            }
            if (f == r) {
                s_comb[h * 8 + r] = bv;
                sgi[h * 8 + r] = tsi[h * 16 + (bf >> 3)] * SUBK + tsi[(h * 2 + 1) * 8 + (bf & 7)];
            }
            if (f == bf) c = -1e300;
        }
    }
    __syncthreads();

    // Phase 4: joint softmax over 32
    if (tid < 32) {
        const int k = tid;
        double s = s_comb[k];
        double m = s;
#pragma unroll
        for (int d = 1; d < 32; d <<= 1) m = fmax(m, __shfl_xor(m, d, 32));
        float e = expf((float)(s - m));
        float sum = e;
#pragma unroll
        for (int d = 1; d < 32; d <<= 1) sum += __shfl_xor(sum, d, 32);
        wsm[k] = e / sum;
    }
    __syncthreads();

    // Phase 5: gather — wave w reads rows 8w..8w+7, all 16 loads in flight
    {
        const int w = tid >> 6, lane = tid & 63;
        float4 v0[8], v1[8];
#pragma unroll
        for (int r = 0; r < 8; ++r) {
            const float* vr = values + (size_t)sgi[w * 8 + r] * VDIM;
            v0[r] = *(const float4*)(vr + lane * 4);
            v1[r] = *(const float4*)(vr + 256 + lane * 4);
        }
        float4 acc0 = {0.f, 0.f, 0.f, 0.f};
        float4 acc1 = {0.f, 0.f, 0.f, 0.f};
#pragma unroll
        for (int r = 0; r < 8; ++r) {
            const float wk = wsm[w * 8 + r];
            acc0.x = fmaf(wk, v0[r].x, acc0.x);
            acc0.y = fmaf(wk, v0[r].y, acc0.y);
            acc0.z = fmaf(wk, v0[r].z, acc0.z);
            acc0.w = fmaf(wk, v0[r].w, acc0.w);
            acc1.x = fmaf(wk, v1[r].x, acc1.x);
            acc1.y = fmaf(wk, v1[r].y, acc1.y);
            acc1.z = fmaf(wk, v1[r].z, acc1.z);
            acc1.w = fmaf(wk, v1[r].w, acc1.w);
        }
        *(float4*)(&part[w * 512 + lane * 4]) = acc0;
        *(float4*)(&part[w * 512 + 256 + lane * 4]) = acc1;
    }
    __syncthreads();

    // Cross-wave reduction + store
    {
        const int c = tid * 2;
        float s0 = part[0 * 512 + c] + part[1 * 512 + c] + part[2 * 512 + c] + part[3 * 512 + c];
        float s1 = part[0 * 512 + c + 1] + part[1 * 512 + c + 1] + part[2 * 512 + c + 1] + part[3 * 512 + c + 1];
        ((float2*)(out + (size_t)n * VDIM))[tid] = make_float2(s0, s1);
    }
}

// ---------------- Pure score kernel: tokens [0, 4096), grid (256,4,2) ----------------
__global__ __launch_bounds__(256) void k_score(
    const float* __restrict__ query, const u16* __restrict__ kb, int* __restrict__ cand)
{
    __shared__ unsigned sc[16 * 513];
    score_body(query, kb, cand, blockIdx.x * 16, blockIdx.y, blockIdx.z, threadIdx.x, sc);
}

// -------- Mixed kernel: grid 6144. i%3==0 -> score tokens 4096+, else sg tokens 0..4095 --------
__global__ __launch_bounds__(256) void k_mixed(
    const float* __restrict__ query, const u16* __restrict__ kb,
    const float* __restrict__ keys, const float* __restrict__ values,
    int* __restrict__ cand, float* __restrict__ out)
{
    __shared__ __align__(16) unsigned char smem[16 * 513 * 4];   // 32832 B arena
    const int i = blockIdx.x;
    const int q = i / 3, m = i - q * 3;
    if (m == 0) {
        // score block: sid = q in 0..2047 -> (nb, h, half)
        const int nb = q & 255, h = (q >> 8) & 3, half = q >> 10;
        score_body(query, kb, cand, 4096 + nb * 16, h, half, threadIdx.x, (unsigned*)smem);
    } else {
        // sg block: token = 2q + (m-1) in 0..4095
        sg_body(query, keys, values, cand, out, 2 * q + (m - 1), threadIdx.x, smem);
    }
}

// ---------------- Pure sg kernel: tokens [4096, 8192), grid 4096 ----------------
__global__ __launch_bounds__(256) void k_sg(
    const float* __restrict__ query, const float* __restrict__ keys,
    const float* __restrict__ values, const int* __restrict__ cand,
    float* __restrict__ out)
{
    __shared__ __align__(16) unsigned char smem[11008];
    sg_body(query, keys, values, cand, out, 4096 + blockIdx.x, threadIdx.x, smem);
}

extern "C" void kernel_launch(void* const* d_in, const int* in_sizes, int n_in,
                              void* d_out, int out_size, void* d_ws, size_t ws_size,
                              hipStream_t stream) {
    const float* query  = (const float*)d_in[0];   // 8192*2048
    const float* keys   = (const float*)d_in[1];   // 4096*256
    const float* values = (const float*)d_in[2];   // 262144*512
    float* out = (float*)d_out;

    char* ws = (char*)d_ws;
    u16* kb   = (u16*)ws;                          // 2,097,152 B
    int* cand = (int*)(ws + 2097152);              // 4,194,304 B

    k_convert<<<512, 256, 0, stream>>>(keys, kb, (2 * N_HEADS * SUBK * HALFD) / 4);

    dim3 gA(256, N_HEADS, 2);
    k_score<<<gA, 256, 0, stream>>>(query, kb, cand);                      // half A

    k_mixed<<<6144, 256, 0, stream>>>(query, kb, keys, values, cand, out); // score B | sg A

    k_sg<<<4096, 256, 0, stream>>>(query, keys, values, cand, out);        // sg B
}

// Round 10
// 387.543 us; speedup vs baseline: 1.0447x; 1.0447x over previous
//
#include <hip/hip_runtime.h>
#include <hip/hip_bf16.h>
#include <math.h>

typedef unsigned short u16;
typedef __attribute__((ext_vector_type(8))) short short8;   // 8 bf16 (4 VGPRs)
typedef __attribute__((ext_vector_type(4))) float f32x4;

#define N_TOK   8192
#define N_HEADS 4
#define KDIM    512
#define HALFD   256
#define VDIM    512
#define SUBK    512
#define NCAND   16

__device__ __forceinline__ u16 f2bf(float f) {
    unsigned u = __float_as_uint(f);
    u += 0x7fffu + ((u >> 16) & 1u);
    return (u16)(u >> 16);
}

__device__ __forceinline__ unsigned med3u(unsigned a, unsigned b, unsigned c) {
    unsigned d;
    asm("v_med3_u32 %0, %1, %2, %3" : "=v"(d) : "v"(a), "v"(b), "v"(c));
    return d;
}

// ---------------- Kernel A: f32 -> bf16 bits (keys only, tiny) ----------------
__global__ void k_convert(const float* __restrict__ in, u16* __restrict__ out, int n4) {
    int i = blockIdx.x * blockDim.x + threadIdx.x;
    int stride = gridDim.x * blockDim.x;
    for (; i < n4; i += stride) {
        float4 v = ((const float4*)in)[i];
        unsigned a = (unsigned)f2bf(v.x) | ((unsigned)f2bf(v.y) << 16);
        unsigned b = (unsigned)f2bf(v.z) | ((unsigned)f2bf(v.w) << 16);
        ((uint2*)out)[i] = make_uint2(a, b);
    }
}

// ------------- Kernel B: bf16 MFMA scores + packed-key exact top-16 -------------
// grid (N/16, HEADS, 2), block 256 (4 waves). Wave w computes s-tiles [8w, 8w+8).
__global__ __launch_bounds__(256) void k_score_topk(
    const float* __restrict__ query,  // [N][2048] f32
    const u16* __restrict__ kb,       // [2][4][512][256] bf16
    int* __restrict__ cand)           // [N][4][2][16]
{
    __shared__ unsigned sc[16 * 513];
    const int nb = blockIdx.x, h = blockIdx.y, half = blockIdx.z;
    const int tid = threadIdx.x;
    const int wave = tid >> 6, l = tid & 63;
    const int lr = l & 15, lk = l >> 4;

    const float* qbase = query + (size_t)(nb * 16 + lr) * (N_HEADS * KDIM)
                       + h * KDIM + half * HALFD + lk * 8;
    short8 a[8];
#pragma unroll
    for (int kf = 0; kf < 8; ++kf) {
        float4 q0 = *(const float4*)(qbase + kf * 32);
        float4 q1 = *(const float4*)(qbase + kf * 32 + 4);
        short8 t;
        t[0] = (short)f2bf(q0.x); t[1] = (short)f2bf(q0.y);
        t[2] = (short)f2bf(q0.z); t[3] = (short)f2bf(q0.w);
        t[4] = (short)f2bf(q1.x); t[5] = (short)f2bf(q1.y);
        t[6] = (short)f2bf(q1.z); t[7] = (short)f2bf(q1.w);
        a[kf] = t;
    }

    const u16* kbase = kb + (size_t)(half * N_HEADS + h) * SUBK * HALFD;
#pragma unroll
    for (int t = 0; t < 8; ++t) {
        const int st = wave * 8 + t;
        const u16* kp = kbase + (size_t)(st * 16 + lr) * HALFD + lk * 8;
        short8 b[8];
#pragma unroll
        for (int kf = 0; kf < 8; ++kf)
            b[kf] = *(const short8*)(kp + kf * 32);
        f32x4 acc = {0.f, 0.f, 0.f, 0.f};
#pragma unroll
        for (int kf = 0; kf < 8; ++kf)
            acc = __builtin_amdgcn_mfma_f32_16x16x32_bf16(a[kf], b[kf], acc, 0, 0, 0);
#pragma unroll
        for (int r = 0; r < 4; ++r) {
            unsigned ub = __float_as_uint(acc[r]);
            unsigned key = ub ^ ((unsigned)((int)ub >> 31) | 0x80000000u);
            key = (key & 0xFFFFFE00u) | (unsigned)(st * 16 + lr);
            sc[(lk * 4 + r) * 513 + st * 16 + lr] = key;
        }
    }
    __syncthreads();

    const int row = tid >> 4, sub = tid & 15;
    unsigned tv[NCAND];
#pragma unroll
    for (int j = 0; j < NCAND; ++j) tv[j] = 0u;
    const int base = row * 513 + sub;
#pragma unroll
    for (int t = 0; t < 32; ++t) {
        unsigned v = sc[base + (t << 4)];
#pragma unroll
        for (int j = NCAND - 1; j >= 1; --j)
            tv[j] = med3u(tv[j - 1], tv[j], v);
        tv[0] = (tv[0] > v) ? tv[0] : v;
    }

    unsigned keep = 0;
#pragma unroll
    for (int r = 0; r < NCAND; ++r) {
        unsigned w = tv[0];
#pragma unroll
        for (int d = 1; d < 16; d <<= 1) {
            unsigned o = __shfl_xor(w, d, 16);
            w = (o > w) ? o : w;
        }
        if (sub == r) keep = w;
        bool pop = (tv[0] == w);
#pragma unroll
        for (int j = 0; j < NCAND - 1; ++j) tv[j] = pop ? tv[j + 1] : tv[j];
        tv[NCAND - 1] = pop ? 0u : tv[NCAND - 1];
    }
    const int n = nb * 16 + row;
    cand[((size_t)n * 8 + (h * 2 + half)) * NCAND + sub] = (int)(keep & 0x1FFu);
}

// --- Kernel C: f64 refine + exact 2-stage top-8 + softmax + deep row-per-wave gather ---
// grid = N, block = 256 (4 waves)
__global__ __launch_bounds__(256) void k_select_gather(
    const float* __restrict__ query,   // [N][2048]
    const float* __restrict__ keys,    // [2][4][512][256]
    const float* __restrict__ values,  // [262144][512]
    const int* __restrict__ cand,      // [N][8][16]
    float* __restrict__ out)           // [N][512]
{
    __shared__ double rv[8][16];
    __shared__ int    ri[8][16];
    __shared__ double tsv[8][8];
    __shared__ int    tsi[8][8];
    __shared__ double s_comb[32];
    __shared__ int    sgi[32];
    __shared__ float  wsm[32];
    __shared__ float  part[4][512];    // cross-wave gather partials (8 KB)

    const int n = blockIdx.x;
    const int tid = threadIdx.x;

    // Phase 1: f64 refinement, 2 threads per candidate dot (128 dims each)
    {
        const int dot = tid >> 1, pt = tid & 1;
        const int g = dot >> 4, j = dot & 15;
        const int h = g >> 1, half = g & 1;
        const int sidx = cand[((size_t)n * 8 + g) * NCAND + j];
        const float* qrow = query + (size_t)n * (N_HEADS * KDIM) + h * KDIM + half * HALFD + pt * 128;
        const float* krow = keys + ((size_t)(half * N_HEADS + h) * SUBK + sidx) * HALFD + pt * 128;
        double a0 = 0, a1 = 0, a2 = 0, a3 = 0;
#pragma unroll 8
        for (int d = 0; d < 128; d += 4) {
            float4 qv = *(const float4*)(qrow + d);
            float4 kv = *(const float4*)(krow + d);
            a0 = fma((double)qv.x, (double)kv.x, a0);
            a1 = fma((double)qv.y, (double)kv.y, a1);
            a2 = fma((double)qv.z, (double)kv.z, a2);
            a3 = fma((double)qv.w, (double)kv.w, a3);
        }
        double s = (a0 + a1) + (a2 + a3);
        double o = __shfl_xor(s, 1);
        if (pt == 0) { rv[g][j] = s + o; ri[g][j] = sidx; }
    }
    __syncthreads();

    // Phase 2: top-8 of 16 per group, 16 lanes/group, shfl argmax (tie -> lowest j)
    if (tid < 128) {
        const int g = tid >> 4, j = tid & 15;
        double v = rv[g][j];
        const int idx = ri[g][j];
        for (int r = 0; r < 8; ++r) {
            double bv = v; int bj = j;
#pragma unroll
            for (int d = 1; d < 16; d <<= 1) {
                double ov = __shfl_xor(bv, d, 16);
                int    oj = __shfl_xor(bj, d, 16);
                if (ov > bv || (ov == bv && oj < bj)) { bv = ov; bj = oj; }
            }
            int widx = __shfl(idx, bj, 16);
            if (j == r) { tsv[g][r] = bv; tsi[g][r] = widx; }
            if (j == bj) v = -1e300;
        }
    }
    __syncthreads();

    // Phase 3: per head (one wave each), top-8 of 64 combos (tie -> lowest flat f)
    {
        const int h = tid >> 6, f = tid & 63;
        double c = tsv[h * 2][f >> 3] + tsv[h * 2 + 1][f & 7];
        for (int r = 0; r < 8; ++r) {
            double bv = c; int bf = f;
#pragma unroll
            for (int d = 1; d < 64; d <<= 1) {
                double ov = __shfl_xor(bv, d, 64);
                int    of = __shfl_xor(bf, d, 64);
                if (ov > bv || (ov == bv && of < bf)) { bv = ov; bf = of; }
            }
            if (f == r) {
                s_comb[h * 8 + r] = bv;
                sgi[h * 8 + r] = tsi[h * 2][bf >> 3] * SUBK + tsi[h * 2 + 1][bf & 7];
            }
            if (f == bf) c = -1e300;
        }
    }
    __syncthreads();

    // Phase 4: joint softmax over 32 (parallel, f32 exp after f64 max-subtract)
    if (tid < 32) {
        const int k = tid;
        double s = s_comb[k];
        double m = s;
#pragma unroll
        for (int d = 1; d < 32; d <<= 1) m = fmax(m, __shfl_xor(m, d, 32));
        float e = expf((float)(s - m));
        float sum = e;
#pragma unroll
        for (int d = 1; d < 32; d <<= 1) sum += __shfl_xor(sum, d, 32);
        wsm[k] = e / sum;
    }
    __syncthreads();

    // Phase 5: gather — wave w reads rows 8w..8w+7 (2 KB each, as 2x 1 KB
    // dwordx4 bursts). ALL 16 loads issued before any FMA: 16 vmem ops in
    // flight per wave, no exposed second-batch latency at the token tail.
    {
        const int w = tid >> 6, lane = tid & 63;
        float4 v0[8], v1[8];
#pragma unroll
        for (int r = 0; r < 8; ++r) {
            const float* vr = values + (size_t)sgi[w * 8 + r] * VDIM;
            v0[r] = *(const float4*)(vr + lane * 4);
            v1[r] = *(const float4*)(vr + 256 + lane * 4);
        }
        float4 acc0 = {0.f, 0.f, 0.f, 0.f};
        float4 acc1 = {0.f, 0.f, 0.f, 0.f};
#pragma unroll
        for (int r = 0; r < 8; ++r) {
            const float wk = wsm[w * 8 + r];
            acc0.x = fmaf(wk, v0[r].x, acc0.x);
            acc0.y = fmaf(wk, v0[r].y, acc0.y);
            acc0.z = fmaf(wk, v0[r].z, acc0.z);
            acc0.w = fmaf(wk, v0[r].w, acc0.w);
            acc1.x = fmaf(wk, v1[r].x, acc1.x);
            acc1.y = fmaf(wk, v1[r].y, acc1.y);
            acc1.z = fmaf(wk, v1[r].z, acc1.z);
            acc1.w = fmaf(wk, v1[r].w, acc1.w);
        }
        *(float4*)(&part[w][lane * 4]) = acc0;
        *(float4*)(&part[w][256 + lane * 4]) = acc1;
    }
    __syncthreads();

    // Cross-wave reduction: thread t sums 4 partials for cols [2t, 2t+1]
    {
        const int c = tid * 2;
        float s0 = part[0][c]     + part[1][c]     + part[2][c]     + part[3][c];
        float s1 = part[0][c + 1] + part[1][c + 1] + part[2][c + 1] + part[3][c + 1];
        ((float2*)(out + (size_t)n * VDIM))[tid] = make_float2(s0, s1);
    }
}

extern "C" void kernel_launch(void* const* d_in, const int* in_sizes, int n_in,
                              void* d_out, int out_size, void* d_ws, size_t ws_size,
                              hipStream_t stream) {
    const float* query  = (const float*)d_in[0];   // 8192*2048
    const float* keys   = (const float*)d_in[1];   // 4096*256
    const float* values = (const float*)d_in[2];   // 262144*512
    float* out = (float*)d_out;

    char* ws = (char*)d_ws;
    u16* kb   = (u16*)ws;                          // 2,097,152 B
    int* cand = (int*)(ws + 2097152);              // 4,194,304 B

    k_convert<<<512, 256, 0, stream>>>(keys, kb, (2 * N_HEADS * SUBK * HALFD) / 4);

    dim3 gB(N_TOK / 16, N_HEADS, 2);
    k_score_topk<<<gB, 256, 0, stream>>>(query, kb, cand);

    k_select_gather<<<N_TOK, 256, 0, stream>>>(query, keys, values, cand, out);
}